// Round 7
// baseline (57.317 us; speedup 1.0000x reference)
//
#include <hip/hip_runtime.h>
#include <utility>

typedef __attribute__((ext_vector_type(8))) short short8;
typedef __attribute__((ext_vector_type(4))) float f32x4;
typedef unsigned short u16;

#define NROW 32768   // circuits = 4096*8
#define KDIM 256
#define NOUT 512

// ---------------- gate tables (kind: 0=ry 1=rx 2=xx 3=xy 4=cry 5=crx) --------
static constexpr unsigned char cGK[114] = {
  0,0,0,0,0,0,0,0,0,             // ry 0-8
  1,1,1,1,1,1,1,1,1,             // rx 9-17
  2,2,2,2,2,2,2,2,               // xx 18-25
  4,4,4,4,4,4,4,4,               // cry 26-33
  0,0,0,0,0,0,0,0,0,             // ry 34-42
  3,3,3,3,3,3,3,3,               // xy 43-50
  5,5,5,5,5,5,                   // crx 51-56
  1,1,1,1,1,1,1,1,1,             // rx 57-65
  2,2,2,2,2,2,2,2,               // xx 66-73
  4,4,4,4,4,4,4,4,               // cry 74-81
  0,0,0,0,0,0,0,0,0,             // ry 82-90
  3,3,3,3,3,3,3,3,               // xy 91-98
  5,5,5,5,5,5,                   // crx 99-104
  1,1,1,1,1,1,1,1,1              // rx 105-113
};
static constexpr unsigned char cGW0[114] = {
  0,1,2,3,4,5,6,7,8,
  0,1,2,3,4,5,6,7,8,
  0,8,1,7,2,6,3,5,
  0,1,2,8,7,6,5,3,
  0,1,2,3,4,5,6,7,8,
  4,4,3,5,2,6,1,7,
  0,2,5,7,1,6,
  0,1,2,3,4,5,6,7,8,
  0,8,1,7,2,6,3,5,
  0,1,2,8,7,6,5,3,
  0,1,2,3,4,5,6,7,8,
  4,4,3,5,2,6,1,7,
  0,2,5,7,1,6,
  0,1,2,3,4,5,6,7,8
};
static constexpr unsigned char cGW1[114] = {
  0,0,0,0,0,0,0,0,0,
  0,0,0,0,0,0,0,0,0,
  1,7,2,6,3,5,4,4,
  1,2,3,7,6,5,4,4,
  0,0,0,0,0,0,0,0,0,
  3,5,2,6,1,7,0,8,
  1,3,6,8,2,7,
  0,0,0,0,0,0,0,0,0,
  1,7,2,6,3,5,4,4,
  1,2,3,7,6,5,4,4,
  0,0,0,0,0,0,0,0,0,
  3,5,2,6,1,7,0,8,
  1,3,6,8,2,7,
  0,0,0,0,0,0,0,0,0
};

__device__ __forceinline__ u16 f2bf(float f) {
  unsigned int u = __float_as_uint(f);
  u = (u + 0x7fffu + ((u >> 16) & 1u)) >> 16;
  return (u16)u;
}
__device__ __forceinline__ float bf2f(u16 b) {
  return __uint_as_float(((unsigned int)b) << 16);
}

typedef const __attribute__((address_space(1))) unsigned int* gptr_t;
typedef __attribute__((address_space(3))) unsigned int* lptr_t;
__device__ __forceinline__ void gload16(const void* g, void* l) {
  __builtin_amdgcn_global_load_lds((gptr_t)g, (lptr_t)l, 16, 0, 0);
}

// ---------------- fused kernel 1: build_m (blocks 0..63) + prep_g (rest) ----
template <int G>
__device__ __forceinline__ void apply_gate(float (&re)[8], float (&im)[8],
                                           float c0v, float s0v, float c1v,
                                           float s1v, int l) {
  constexpr int kind = cGK[G];
  constexpr int p0 = 8 - cGW0[G];
  constexpr int p1 = 8 - cGW1[G];
  constexpr int m = (kind <= 1) ? (1 << p0)
                  : (kind <= 3) ? ((1 << p0) | (1 << p1))
                  : (1 << p1);   // controlled: flip target bit only
  constexpr int ml = m & 63;
  constexpr int mr = m >> 6;
  float c = __shfl((G < 64) ? c0v : c1v, G & 63, 64);
  float s = __shfl((G < 64) ? s0v : s1v, G & 63, 64);
  float br[8], bi[8];
  #pragma unroll
  for (int r = 0; r < 8; ++r) { br[r] = re[r ^ mr]; bi[r] = im[r ^ mr]; }
  if constexpr (ml != 0) {
    #pragma unroll
    for (int r = 0; r < 8; ++r) {
      br[r] = __shfl_xor(br[r], ml, 64);
      bi[r] = __shfl_xor(bi[r], ml, 64);
    }
  }
  #pragma unroll
  for (int r = 0; r < 8; ++r) {
    const int idx = (r << 6) | l;
    float nre, nim;
    if constexpr (kind == 0) {               // ry
      float sg = ((idx >> p0) & 1) ? s : -s;
      nre = c * re[r] + sg * br[r];
      nim = c * im[r] + sg * bi[r];
    } else if constexpr (kind == 1 || kind == 2) {  // rx / xx
      nre = c * re[r] + s * bi[r];
      nim = c * im[r] - s * br[r];
    } else if constexpr (kind == 3) {        // xy
      bool ap = (((idx >> p0) ^ (idx >> p1)) & 1) != 0;
      nre = ap ? (c * re[r] - s * bi[r]) : re[r];
      nim = ap ? (c * im[r] + s * br[r]) : im[r];
    } else if constexpr (kind == 4) {        // cry
      bool ap = ((idx >> p0) & 1) != 0;
      float sg = ((idx >> p1) & 1) ? s : -s;
      nre = ap ? (c * re[r] + sg * br[r]) : re[r];
      nim = ap ? (c * im[r] + sg * bi[r]) : im[r];
    } else {                                 // crx
      bool ap = ((idx >> p0) & 1) != 0;
      nre = ap ? (c * re[r] + s * bi[r]) : re[r];
      nim = ap ? (c * im[r] - s * br[r]) : im[r];
    }
    re[r] = nre; im[r] = nim;
  }
}

template <int... Gs>
__device__ __forceinline__ void apply_all(std::integer_sequence<int, Gs...>,
                                          float (&re)[8], float (&im)[8],
                                          float c0v, float s0v, float c1v,
                                          float s1v, int l) {
  (apply_gate<Gs>(re, im, c0v, s0v, c1v, s1v, l), ...);
}

__global__ void __launch_bounds__(256) prep_build(
    const float* __restrict__ x, const float* __restrict__ qp,
    u16* __restrict__ G, float* __restrict__ invn2, u16* __restrict__ BreT,
    u16* __restrict__ BimT) {
  int bid = blockIdx.x;
  int tid = threadIdx.x;
  int l = tid & 63;
  if (bid < 64) {
    // ---- build role: wave w -> column k = bid*4 + w ----
    int k = bid * 4 + (tid >> 6);
    float a0 = qp[l] * 0.5f;                        // gates 0..63
    float a1 = (l < 50) ? qp[l + 64] * 0.5f : 0.f;  // gates 64..113
    float c0v = cosf(a0), s0v = sinf(a0);
    float c1v = cosf(a1), s1v = sinf(a1);

    int col = ((k >> 4) << 5) | (k & 15);  // wire 4 stays |0>
    float re[8], im[8];
    #pragma unroll
    for (int r = 0; r < 8; ++r) {
      re[r] = (r == (col >> 6) && l == (col & 63)) ? 1.f : 0.f;
      im[r] = 0.f;
    }
    apply_all(std::make_integer_sequence<int, 114>{}, re, im, c0v, s0v, c1v,
              s1v, l);
    #pragma unroll
    for (int r = 0; r < 8; ++r) {
      int j = (r << 6) | l;
      BreT[(size_t)j * KDIM + k] = f2bf(re[r]);
      BimT[(size_t)j * KDIM + k] = f2bf(im[r]);
    }
  } else {
    // ---- prep role: wave per row ----
    int gid = (bid - 64) * 256 + tid;
    int row = gid >> 6;
    const float H = 1.5707963267948966f;
    float4 v = *(const float4*)(x + ((size_t)row << 8) + l * 4);
    float g0 = tanhf(v.x) * H, g1 = tanhf(v.y) * H;
    float g2 = tanhf(v.z) * H, g3 = tanhf(v.w) * H;
    u16 b0 = f2bf(g0), b1 = f2bf(g1), b2 = f2bf(g2), b3 = f2bf(g3);
    float r0 = bf2f(b0), r1 = bf2f(b1), r2 = bf2f(b2), r3 = bf2f(b3);
    float sum = r0 * r0 + r1 * r1 + r2 * r2 + r3 * r3;
    #pragma unroll
    for (int o = 32; o; o >>= 1) sum += __shfl_xor(sum, o, 64);
    ushort4 pk; pk.x = b0; pk.y = b1; pk.z = b2; pk.w = b3;
    *(ushort4*)(G + ((size_t)row << 8) + l * 4) = pk;
    if (l == 0) invn2[row] = 1.0f / sum;
  }
}

// ---------------- kernel 2: GEMM + |.|^2 epilogue ---------------------------
// BM=128 BN=32 BK=64, 4 waves, single-buffered LDS 24KB, low VGPR ->
// 4-5 blocks/CU resident: short-K GEMM hides stage latency via TLP across
// blocks (m114), not in-block pipelining (R5 dbuf was neutral). Grid 4096 =
// 256 row-panels x 16 n-blocks; XCD-chunked: XCD x owns panels x*32..x*32+31
// -> per-XCD A slice 2MB (L2-fit), B 512KB broadcast.
__global__ void __launch_bounds__(256) gemm_probs(
    const u16* __restrict__ G, const u16* __restrict__ BreT,
    const u16* __restrict__ BimT, const float* __restrict__ invn2,
    float* __restrict__ out) {
  __shared__ __align__(16) char lds[24576];
  char* sA = lds;            // 128 rows x 128B = 16KB
  char* sBre = lds + 16384;  // 32 x 128B = 4KB
  char* sBim = lds + 20480;  // 4KB
  int tid = threadIdx.x;
  int l = tid & 63;
  int w = tid >> 6;
  int bid = blockIdx.x;                 // 0..4095
  int xcd = bid & 7;
  int idx = bid >> 3;                   // 0..511
  int panel = xcd * 32 + (idx & 31);    // row-panel 0..255, chunked per XCD
  int nblk = idx >> 5;                  // 0..15
  int row0 = panel * 128;
  int n0 = nblk * 32;

  f32x4 accre[2][2] = {};
  f32x4 accim[2][2] = {};

  for (int k0 = 0; k0 < KDIM; k0 += 64) {
    __syncthreads();
    // stage A tile: 16 segs of 8 rows (1KB each); XOR-swizzle on SOURCE addr
    #pragma unroll
    for (int i = 0; i < 4; ++i) {
      int sg = w * 4 + i;
      int row = sg * 8 + (l >> 3);
      int chunk = (l & 7) ^ (row & 7);
      gload16(G + (size_t)(row0 + row) * KDIM + k0 + chunk * 8, sA + sg * 1024);
    }
    // stage B tiles: 4 segs each; wave w stages seg w of Bre and Bim
    {
      int rn = w * 8 + (l >> 3);
      int chunk = (l & 7) ^ (rn & 7);
      size_t off = (size_t)(n0 + rn) * KDIM + k0 + chunk * 8;
      gload16(BreT + off, sBre + w * 1024);
      gload16(BimT + off, sBim + w * 1024);
    }
    asm volatile("s_waitcnt vmcnt(0)" ::: "memory");
    __syncthreads();

    #pragma unroll
    for (int kk = 0; kk < 2; ++kk) {
      short8 aF[2], brF[2], biF[2];
      #pragma unroll
      for (int mr = 0; mr < 2; ++mr) {
        int row = w * 32 + mr * 16 + (l & 15);
        int chunk = (kk * 4 + (l >> 4)) ^ (row & 7);
        aF[mr] = *(const short8*)(sA + row * 128 + chunk * 16);
      }
      #pragma unroll
      for (int nb = 0; nb < 2; ++nb) {
        int rn = nb * 16 + (l & 15);
        int chunk = (kk * 4 + (l >> 4)) ^ (rn & 7);
        brF[nb] = *(const short8*)(sBre + rn * 128 + chunk * 16);
        biF[nb] = *(const short8*)(sBim + rn * 128 + chunk * 16);
      }
      #pragma unroll
      for (int mr = 0; mr < 2; ++mr)
        #pragma unroll
        for (int nb = 0; nb < 2; ++nb) {
          accre[mr][nb] = __builtin_amdgcn_mfma_f32_16x16x32_bf16(
              aF[mr], brF[nb], accre[mr][nb], 0, 0, 0);
          accim[mr][nb] = __builtin_amdgcn_mfma_f32_16x16x32_bf16(
              aF[mr], biF[nb], accim[mr][nb], 0, 0, 0);
        }
    }
  }

  // epilogue: C/D layout col=lane&15, row=(lane>>4)*4+reg
  #pragma unroll
  for (int mr = 0; mr < 2; ++mr) {
    int rbase = row0 + w * 32 + mr * 16 + (l >> 4) * 4;
    #pragma unroll
    for (int reg = 0; reg < 4; ++reg) {
      float inv = invn2[rbase + reg];
      #pragma unroll
      for (int nb = 0; nb < 2; ++nb) {
        float re = accre[mr][nb][reg];
        float im = accim[mr][nb][reg];
        __builtin_nontemporal_store(
            (re * re + im * im) * inv,
            out + (size_t)(rbase + reg) * NOUT + n0 + nb * 16 + (l & 15));
      }
    }
  }
}

extern "C" void kernel_launch(void* const* d_in, const int* in_sizes, int n_in,
                              void* d_out, int out_size, void* d_ws,
                              size_t ws_size, hipStream_t stream) {
  const float* x = (const float*)d_in[0];   // (4096, 2048) f32
  const float* qp = (const float*)d_in[1];  // (114,) f32
  float* out = (float*)d_out;               // 32768*512 f32
  char* ws = (char*)d_ws;
  u16* G = (u16*)ws;                                   // 16 MB
  u16* BreT = (u16*)(ws + (16u << 20));                // 256 KB
  u16* BimT = (u16*)(ws + (16u << 20) + (256u << 10)); // 256 KB
  float* invn2 = (float*)(ws + (16u << 20) + (512u << 10));  // 128 KB

  hipLaunchKernelGGL(prep_build, dim3(64 + NROW / 4), dim3(256), 0, stream, x,
                     qp, G, invn2, BreT, BimT);
  hipLaunchKernelGGL(gemm_probs, dim3(4096), dim3(256), 0, stream, G, BreT,
                     BimT, invn2, out);
}

// Round 8
// 54.559 us; speedup vs baseline: 1.0505x; 1.0505x over previous
//
#include <hip/hip_runtime.h>
#include <utility>

typedef __attribute__((ext_vector_type(8))) short short8;
typedef __attribute__((ext_vector_type(4))) float f32x4;
typedef unsigned short u16;

#define NROW 32768   // circuits = 4096*8
#define KDIM 256
#define NOUT 512

// ---------------- gate tables (kind: 0=ry 1=rx 2=xx 3=xy 4=cry 5=crx) --------
static constexpr unsigned char cGK[114] = {
  0,0,0,0,0,0,0,0,0,             // ry 0-8
  1,1,1,1,1,1,1,1,1,             // rx 9-17
  2,2,2,2,2,2,2,2,               // xx 18-25
  4,4,4,4,4,4,4,4,               // cry 26-33
  0,0,0,0,0,0,0,0,0,             // ry 34-42
  3,3,3,3,3,3,3,3,               // xy 43-50
  5,5,5,5,5,5,                   // crx 51-56
  1,1,1,1,1,1,1,1,1,             // rx 57-65
  2,2,2,2,2,2,2,2,               // xx 66-73
  4,4,4,4,4,4,4,4,               // cry 74-81
  0,0,0,0,0,0,0,0,0,             // ry 82-90
  3,3,3,3,3,3,3,3,               // xy 91-98
  5,5,5,5,5,5,                   // crx 99-104
  1,1,1,1,1,1,1,1,1              // rx 105-113
};
static constexpr unsigned char cGW0[114] = {
  0,1,2,3,4,5,6,7,8,
  0,1,2,3,4,5,6,7,8,
  0,8,1,7,2,6,3,5,
  0,1,2,8,7,6,5,3,
  0,1,2,3,4,5,6,7,8,
  4,4,3,5,2,6,1,7,
  0,2,5,7,1,6,
  0,1,2,3,4,5,6,7,8,
  0,8,1,7,2,6,3,5,
  0,1,2,8,7,6,5,3,
  0,1,2,3,4,5,6,7,8,
  4,4,3,5,2,6,1,7,
  0,2,5,7,1,6,
  0,1,2,3,4,5,6,7,8
};
static constexpr unsigned char cGW1[114] = {
  0,0,0,0,0,0,0,0,0,
  0,0,0,0,0,0,0,0,0,
  1,7,2,6,3,5,4,4,
  1,2,3,7,6,5,4,4,
  0,0,0,0,0,0,0,0,0,
  3,5,2,6,1,7,0,8,
  1,3,6,8,2,7,
  0,0,0,0,0,0,0,0,0,
  1,7,2,6,3,5,4,4,
  1,2,3,7,6,5,4,4,
  0,0,0,0,0,0,0,0,0,
  3,5,2,6,1,7,0,8,
  1,3,6,8,2,7,
  0,0,0,0,0,0,0,0,0
};

__device__ __forceinline__ u16 f2bf(float f) {
  unsigned int u = __float_as_uint(f);
  u = (u + 0x7fffu + ((u >> 16) & 1u)) >> 16;
  return (u16)u;
}
__device__ __forceinline__ float bf2f(u16 b) {
  return __uint_as_float(((unsigned int)b) << 16);
}

// fast tanh: (e^{2x}-1)/(e^{2x}+1) via hw exp+rcp. Upper clamp avoids inf/inf;
// lower side underflows to exact -1. ulp-level error << bf16 quantization.
__device__ __forceinline__ float fast_tanh(float x) {
  float xc = fminf(x, 15.f);
  float e = __expf(2.f * xc);
  return 1.f - 2.f * __builtin_amdgcn_rcpf(e + 1.f);
}

typedef const __attribute__((address_space(1))) unsigned int* gptr_t;
typedef __attribute__((address_space(3))) unsigned int* lptr_t;
__device__ __forceinline__ void gload16(const void* g, void* l) {
  __builtin_amdgcn_global_load_lds((gptr_t)g, (lptr_t)l, 16, 0, 0);
}

// ---------------- fused kernel 1: build_m (blocks 0..63) + prep_g (rest) ----
template <int G>
__device__ __forceinline__ void apply_gate(float (&re)[8], float (&im)[8],
                                           float c0v, float s0v, float c1v,
                                           float s1v, int l) {
  constexpr int kind = cGK[G];
  constexpr int p0 = 8 - cGW0[G];
  constexpr int p1 = 8 - cGW1[G];
  constexpr int m = (kind <= 1) ? (1 << p0)
                  : (kind <= 3) ? ((1 << p0) | (1 << p1))
                  : (1 << p1);   // controlled: flip target bit only
  constexpr int ml = m & 63;
  constexpr int mr = m >> 6;
  float c = __shfl((G < 64) ? c0v : c1v, G & 63, 64);
  float s = __shfl((G < 64) ? s0v : s1v, G & 63, 64);
  float br[8], bi[8];
  #pragma unroll
  for (int r = 0; r < 8; ++r) { br[r] = re[r ^ mr]; bi[r] = im[r ^ mr]; }
  if constexpr (ml != 0) {
    #pragma unroll
    for (int r = 0; r < 8; ++r) {
      br[r] = __shfl_xor(br[r], ml, 64);
      bi[r] = __shfl_xor(bi[r], ml, 64);
    }
  }
  #pragma unroll
  for (int r = 0; r < 8; ++r) {
    const int idx = (r << 6) | l;
    float nre, nim;
    if constexpr (kind == 0) {               // ry
      float sg = ((idx >> p0) & 1) ? s : -s;
      nre = c * re[r] + sg * br[r];
      nim = c * im[r] + sg * bi[r];
    } else if constexpr (kind == 1 || kind == 2) {  // rx / xx
      nre = c * re[r] + s * bi[r];
      nim = c * im[r] - s * br[r];
    } else if constexpr (kind == 3) {        // xy
      bool ap = (((idx >> p0) ^ (idx >> p1)) & 1) != 0;
      nre = ap ? (c * re[r] - s * bi[r]) : re[r];
      nim = ap ? (c * im[r] + s * br[r]) : im[r];
    } else if constexpr (kind == 4) {        // cry
      bool ap = ((idx >> p0) & 1) != 0;
      float sg = ((idx >> p1) & 1) ? s : -s;
      nre = ap ? (c * re[r] + sg * br[r]) : re[r];
      nim = ap ? (c * im[r] + sg * bi[r]) : im[r];
    } else {                                 // crx
      bool ap = ((idx >> p0) & 1) != 0;
      nre = ap ? (c * re[r] + s * bi[r]) : re[r];
      nim = ap ? (c * im[r] - s * br[r]) : im[r];
    }
    re[r] = nre; im[r] = nim;
  }
}

template <int... Gs>
__device__ __forceinline__ void apply_all(std::integer_sequence<int, Gs...>,
                                          float (&re)[8], float (&im)[8],
                                          float c0v, float s0v, float c1v,
                                          float s1v, int l) {
  (apply_gate<Gs>(re, im, c0v, s0v, c1v, s1v, l), ...);
}

__global__ void __launch_bounds__(256) prep_build(
    const float* __restrict__ x, const float* __restrict__ qp,
    u16* __restrict__ G, float* __restrict__ invn2, u16* __restrict__ BreT,
    u16* __restrict__ BimT) {
  int bid = blockIdx.x;
  int tid = threadIdx.x;
  int l = tid & 63;
  if (bid < 64) {
    // ---- build role: wave w -> column k = bid*4 + w ----
    int k = bid * 4 + (tid >> 6);
    float a0 = qp[l] * 0.5f;                        // gates 0..63
    float a1 = (l < 50) ? qp[l + 64] * 0.5f : 0.f;  // gates 64..113
    float c0v = cosf(a0), s0v = sinf(a0);
    float c1v = cosf(a1), s1v = sinf(a1);

    int col = ((k >> 4) << 5) | (k & 15);  // wire 4 stays |0>
    float re[8], im[8];
    #pragma unroll
    for (int r = 0; r < 8; ++r) {
      re[r] = (r == (col >> 6) && l == (col & 63)) ? 1.f : 0.f;
      im[r] = 0.f;
    }
    apply_all(std::make_integer_sequence<int, 114>{}, re, im, c0v, s0v, c1v,
              s1v, l);
    #pragma unroll
    for (int r = 0; r < 8; ++r) {
      int j = (r << 6) | l;
      BreT[(size_t)j * KDIM + k] = f2bf(re[r]);
      BimT[(size_t)j * KDIM + k] = f2bf(im[r]);
    }
  } else {
    // ---- prep role: wave per row ----
    int gid = (bid - 64) * 256 + tid;
    int row = gid >> 6;
    const float H = 1.5707963267948966f;
    float4 v = *(const float4*)(x + ((size_t)row << 8) + l * 4);
    float g0 = fast_tanh(v.x) * H, g1 = fast_tanh(v.y) * H;
    float g2 = fast_tanh(v.z) * H, g3 = fast_tanh(v.w) * H;
    u16 b0 = f2bf(g0), b1 = f2bf(g1), b2 = f2bf(g2), b3 = f2bf(g3);
    float r0 = bf2f(b0), r1 = bf2f(b1), r2 = bf2f(b2), r3 = bf2f(b3);
    float sum = r0 * r0 + r1 * r1 + r2 * r2 + r3 * r3;
    #pragma unroll
    for (int o = 32; o; o >>= 1) sum += __shfl_xor(sum, o, 64);
    ushort4 pk; pk.x = b0; pk.y = b1; pk.z = b2; pk.w = b3;
    *(ushort4*)(G + ((size_t)row << 8) + l * 4) = pk;
    if (l == 0) invn2[row] = 1.0f / sum;
  }
}

// ---------------- kernel 2: GEMM + |.|^2 epilogue ---------------------------
// BM=128 BN=64 BK=64, 4 waves, single-buffered 32KB LDS (R4 geometry; R5 dbuf
// and R7 small-tile were both neutral). Per-kk fragment loads keep live VGPRs
// low. Grid 2048; XCD swizzle: XCD x owns nw x*256..x*256+255, n0 fast ->
// A-panel reuse distance 8 blocks, B fully L2-resident.
__global__ void __launch_bounds__(256) gemm_probs(
    const u16* __restrict__ G, const u16* __restrict__ BreT,
    const u16* __restrict__ BimT, const float* __restrict__ invn2,
    float* __restrict__ out) {
  __shared__ __align__(16) char lds[32768];
  char* sA = lds;            // 128 rows x 128B = 16KB
  char* sBre = lds + 16384;  // 64 x 128B = 8KB
  char* sBim = lds + 24576;  // 8KB
  int tid = threadIdx.x;
  int l = tid & 63;
  int w = tid >> 6;
  int bid = blockIdx.x;                       // 0..2047
  int nw = (bid & 7) * 256 + (bid >> 3);      // bijective XCD swizzle
  int row0 = (nw >> 3) * 128;
  int n0 = (nw & 7) * 64;

  f32x4 accre[2][4] = {};
  f32x4 accim[2][4] = {};

  for (int k0 = 0; k0 < KDIM; k0 += 64) {
    __syncthreads();
    // stage A tile: 16 segs of 8 rows (1KB each); XOR-swizzle on SOURCE addr
    #pragma unroll
    for (int i = 0; i < 4; ++i) {
      int sg = w * 4 + i;
      int row = sg * 8 + (l >> 3);
      int chunk = (l & 7) ^ (row & 7);
      gload16(G + (size_t)(row0 + row) * KDIM + k0 + chunk * 8, sA + sg * 1024);
    }
    // stage B tiles: 8 segs each
    #pragma unroll
    for (int i = 0; i < 2; ++i) {
      int sg = w * 2 + i;
      int rn = sg * 8 + (l >> 3);
      int chunk = (l & 7) ^ (rn & 7);
      size_t off = (size_t)(n0 + rn) * KDIM + k0 + chunk * 8;
      gload16(BreT + off, sBre + sg * 1024);
      gload16(BimT + off, sBim + sg * 1024);
    }
    asm volatile("s_waitcnt vmcnt(0)" ::: "memory");
    __syncthreads();

    #pragma unroll
    for (int kk = 0; kk < 2; ++kk) {
      short8 aF[2], brF[4], biF[4];
      #pragma unroll
      for (int mr = 0; mr < 2; ++mr) {
        int row = w * 32 + mr * 16 + (l & 15);
        int chunk = (kk * 4 + (l >> 4)) ^ (row & 7);
        aF[mr] = *(const short8*)(sA + row * 128 + chunk * 16);
      }
      #pragma unroll
      for (int nb = 0; nb < 4; ++nb) {
        int rn = nb * 16 + (l & 15);
        int chunk = (kk * 4 + (l >> 4)) ^ (rn & 7);
        brF[nb] = *(const short8*)(sBre + rn * 128 + chunk * 16);
        biF[nb] = *(const short8*)(sBim + rn * 128 + chunk * 16);
      }
      #pragma unroll
      for (int mr = 0; mr < 2; ++mr)
        #pragma unroll
        for (int nb = 0; nb < 4; ++nb) {
          accre[mr][nb] = __builtin_amdgcn_mfma_f32_16x16x32_bf16(
              aF[mr], brF[nb], accre[mr][nb], 0, 0, 0);
          accim[mr][nb] = __builtin_amdgcn_mfma_f32_16x16x32_bf16(
              aF[mr], biF[nb], accim[mr][nb], 0, 0, 0);
        }
    }
  }

  // epilogue: C/D layout col=lane&15, row=(lane>>4)*4+reg
  #pragma unroll
  for (int mr = 0; mr < 2; ++mr) {
    int rbase = row0 + w * 32 + mr * 16 + (l >> 4) * 4;
    #pragma unroll
    for (int reg = 0; reg < 4; ++reg) {
      float inv = invn2[rbase + reg];
      #pragma unroll
      for (int nb = 0; nb < 4; ++nb) {
        float re = accre[mr][nb][reg];
        float im = accim[mr][nb][reg];
        __builtin_nontemporal_store(
            (re * re + im * im) * inv,
            out + (size_t)(rbase + reg) * NOUT + n0 + nb * 16 + (l & 15));
      }
    }
  }
}

extern "C" void kernel_launch(void* const* d_in, const int* in_sizes, int n_in,
                              void* d_out, int out_size, void* d_ws,
                              size_t ws_size, hipStream_t stream) {
  const float* x = (const float*)d_in[0];   // (4096, 2048) f32
  const float* qp = (const float*)d_in[1];  // (114,) f32
  float* out = (float*)d_out;               // 32768*512 f32
  char* ws = (char*)d_ws;
  u16* G = (u16*)ws;                                   // 16 MB
  u16* BreT = (u16*)(ws + (16u << 20));                // 256 KB
  u16* BimT = (u16*)(ws + (16u << 20) + (256u << 10)); // 256 KB
  float* invn2 = (float*)(ws + (16u << 20) + (512u << 10));  // 128 KB

  hipLaunchKernelGGL(prep_build, dim3(64 + NROW / 4), dim3(256), 0, stream, x,
                     qp, G, invn2, BreT, BimT);
  hipLaunchKernelGGL(gemm_probs, dim3(2048), dim3(256), 0, stream, G, BreT,
                     BimT, invn2, out);
}